// Round 1
// baseline (184.076 us; speedup 1.0000x reference)
//
#include <hip/hip_runtime.h>
#include <cmath>

#define N_ 32
#define B_ 64
#define T_ 8192
#define CPB 16                      // chunks per b
#define WAVES 4
#define TCHUNK (T_ / (CPB * WAVES)) // 128 t per wave
#define KSTEPS (TCHUNK / 16)        // 8 mfma steps per wave
#define PSTRIDE 2176                // 1024 pp + 1024 pn + 4*32 sums

typedef _Float16 half8 __attribute__((ext_vector_type(8)));
typedef float floatx16 __attribute__((ext_vector_type(16)));

// ---------------- Stage 1: stream inputs, MFMA Grams + fp32 sums ----------------
// grid 1024 = 64 b * 16 chunks; block 256 (4 waves); each wave owns 128 t.
// Pearson is invariant to the reference's per-n affine normalization, so we
// work on raw data (also removes mean-0.5 cancellation the normalized path has).
__global__ __launch_bounds__(256, 4) void k_stage1(const float* __restrict__ pos,
                                                   const float* __restrict__ neg,
                                                   float* __restrict__ partial) {
    __shared__ float lds_g[WAVES][2048];
    __shared__ float lds_s[WAVES][4][32];

    const int bid = blockIdx.x;
    const int b = bid >> 4, c = bid & 15;
    const int tid = threadIdx.x;
    const int w = tid >> 6, lane = tid & 63;
    const int r = lane & 31, h = lane >> 5;

    const long base = ((long)r * B_ + b) * T_;
    const int t0 = (c * WAVES + w) * TCHUNK + h * 8;
    const float4* px = (const float4*)(pos + base + t0);
    const float4* py = (const float4*)(neg + base + t0);

    floatx16 accpp = {};
    floatx16 accpn = {};
    float sx = 0.f, sx2 = 0.f, sy = 0.f, sy2 = 0.f;

#pragma unroll
    for (int s = 0; s < KSTEPS; ++s) {
        float4 xa = px[s * 4 + 0];
        float4 xb = px[s * 4 + 1];
        float4 ya = py[s * 4 + 0];
        float4 yb = py[s * 4 + 1];

        half8 xf, yf;
        xf[0] = (_Float16)xa.x; xf[1] = (_Float16)xa.y;
        xf[2] = (_Float16)xa.z; xf[3] = (_Float16)xa.w;
        xf[4] = (_Float16)xb.x; xf[5] = (_Float16)xb.y;
        xf[6] = (_Float16)xb.z; xf[7] = (_Float16)xb.w;
        yf[0] = (_Float16)ya.x; yf[1] = (_Float16)ya.y;
        yf[2] = (_Float16)ya.z; yf[3] = (_Float16)ya.w;
        yf[4] = (_Float16)yb.x; yf[5] = (_Float16)yb.y;
        yf[6] = (_Float16)yb.z; yf[7] = (_Float16)yb.w;

        // A layout == B layout for this shape: one fragment serves both sides.
        accpp = __builtin_amdgcn_mfma_f32_32x32x16_f16(xf, xf, accpp, 0, 0, 0);
        accpn = __builtin_amdgcn_mfma_f32_32x32x16_f16(xf, yf, accpn, 0, 0, 0);

        sx += xa.x + xa.y + xa.z + xa.w + xb.x + xb.y + xb.z + xb.w;
        sy += ya.x + ya.y + ya.z + ya.w + yb.x + yb.y + yb.z + yb.w;
        sx2 = fmaf(xa.x, xa.x, sx2); sx2 = fmaf(xa.y, xa.y, sx2);
        sx2 = fmaf(xa.z, xa.z, sx2); sx2 = fmaf(xa.w, xa.w, sx2);
        sx2 = fmaf(xb.x, xb.x, sx2); sx2 = fmaf(xb.y, xb.y, sx2);
        sx2 = fmaf(xb.z, xb.z, sx2); sx2 = fmaf(xb.w, xb.w, sx2);
        sy2 = fmaf(ya.x, ya.x, sy2); sy2 = fmaf(ya.y, ya.y, sy2);
        sy2 = fmaf(ya.z, ya.z, sy2); sy2 = fmaf(ya.w, ya.w, sy2);
        sy2 = fmaf(yb.x, yb.x, sy2); sy2 = fmaf(yb.y, yb.y, sy2);
        sy2 = fmaf(yb.z, yb.z, sy2); sy2 = fmaf(yb.w, yb.w, sy2);
    }

    // fold the two half-wave t-slices (lane and lane^32 hold disjoint t)
    sx += __shfl_xor(sx, 32);
    sx2 += __shfl_xor(sx2, 32);
    sy += __shfl_xor(sy, 32);
    sy2 += __shfl_xor(sy2, 32);

    // C/D layout (verified m74/m101): col = lane&31, row = (reg&3)+8*(reg>>2)+4*(lane>>5)
#pragma unroll
    for (int reg = 0; reg < 16; ++reg) {
        int row = (reg & 3) + 8 * (reg >> 2) + 4 * h;
        lds_g[w][row * 32 + r] = accpp[reg];
        lds_g[w][1024 + row * 32 + r] = accpn[reg];
    }
    if (lane < 32) {
        lds_s[w][0][r] = sx;
        lds_s[w][1][r] = sx2;
        lds_s[w][2][r] = sy;
        lds_s[w][3][r] = sy2;
    }
    __syncthreads();

    float* out = partial + (long)bid * PSTRIDE;
    for (int o = tid; o < 2048; o += 256)
        out[o] = lds_g[0][o] + lds_g[1][o] + lds_g[2][o] + lds_g[3][o];
    if (tid < 128) {
        int kind = tid >> 5, row = tid & 31;
        out[2048 + tid] = lds_s[0][kind][row] + lds_s[1][kind][row] +
                          lds_s[2][kind][row] + lds_s[3][kind][row];
    }
}

// ---------------- Stage 2: reduce 16 chunk partials -> per-b stats ----------------
__global__ void k_reduce(const float* __restrict__ partial, float* __restrict__ red) {
    const int b = blockIdx.x;
    const float* in = partial + (long)b * CPB * PSTRIDE;
    float* out = red + (long)b * PSTRIDE;
    for (int o = threadIdx.x; o < PSTRIDE; o += blockDim.x) {
        float s = 0.f;
#pragma unroll
        for (int c = 0; c < CPB; ++c) s += in[c * PSTRIDE + o];
        out[o] = s;
    }
}

// ---------------- Stage 3: per-entry pearson over b, exp terms ----------------
// one wave per (matrix, n, m) entry; lane = b. grid 512 blocks * 4 waves = 2048 entries.
__global__ void k_entries(const float* __restrict__ red, double* __restrict__ blocksums) {
    const int tid = threadIdx.x;
    const int w = tid >> 6, lane = tid & 63;
    const int entry = blockIdx.x * 4 + w;
    const int mat = entry >> 10;       // 0 = pp, 1 = pn
    const int idx = entry & 1023;
    const int n = idx >> 5, m = idx & 31;

    const float* rb = red + (long)lane * PSTRIDE;
    float g = rb[mat * 1024 + idx];
    float sxn = rb[2048 + n];
    float sx2n = rb[2080 + n];
    float sym, sy2m;
    if (mat == 0) {
        sym = rb[2048 + m];
        sy2m = rb[2080 + m];
    } else {
        sym = rb[2112 + m];
        sy2m = rb[2144 + m];
    }

    double num = (double)T_ * (double)g - (double)sxn * (double)sym;
    double vx = (double)T_ * (double)sx2n - (double)sxn * (double)sxn;
    double vy = (double)T_ * (double)sy2m - (double)sym * (double)sym;
    double contrib = 1.0 - num / sqrt(vx * vy);

#pragma unroll
    for (int off = 32; off; off >>= 1) contrib += __shfl_down(contrib, off);

    __shared__ double s_pos[4], s_neg[4];
    if (lane == 0) {
        double d = contrib * (1.0 / B_);
        double term = exp(d / 0.08);
        double p = 0.0, q = 0.0;
        if (mat == 0) {
            if (n < m) p = term;     // strict upper triangle only
        } else {
            q = term;
        }
        s_pos[w] = p;
        s_neg[w] = q;
    }
    __syncthreads();
    if (tid == 0) {
        blocksums[blockIdx.x * 2 + 0] = s_pos[0] + s_pos[1] + s_pos[2] + s_pos[3];
        blocksums[blockIdx.x * 2 + 1] = s_neg[0] + s_neg[1] + s_neg[2] + s_neg[3];
    }
}

// ---------------- Stage 4: final scalar ----------------
__global__ void k_final(const double* __restrict__ blocksums, float* __restrict__ out) {
    __shared__ double sp[256], sn[256];
    const int tid = threadIdx.x;
    double p = 0.0, q = 0.0;
    for (int i = tid; i < 512; i += 256) {
        p += blocksums[2 * i + 0];
        q += blocksums[2 * i + 1];
    }
    sp[tid] = p;
    sn[tid] = q;
    __syncthreads();
    for (int s = 128; s; s >>= 1) {
        if (tid < s) {
            sp[tid] += sp[tid + s];
            sn[tid] += sn[tid + s];
        }
        __syncthreads();
    }
    if (tid == 0) out[0] = (float)log10(sp[0] / sn[0] + 1.0);
}

extern "C" void kernel_launch(void* const* d_in, const int* in_sizes, int n_in,
                              void* d_out, int out_size, void* d_ws, size_t ws_size,
                              hipStream_t stream) {
    const float* pos = (const float*)d_in[0];
    const float* neg = (const float*)d_in[1];
    float* out = (float*)d_out;

    char* ws = (char*)d_ws;
    float* partial = (float*)ws;                               // 1024*2176*4 = 8,912,896 B
    float* red = (float*)(ws + (size_t)1024 * PSTRIDE * 4);    //   64*2176*4 =   557,056 B
    double* blocksums = (double*)(ws + (size_t)1024 * PSTRIDE * 4 + (size_t)64 * PSTRIDE * 4);

    k_stage1<<<1024, 256, 0, stream>>>(pos, neg, partial);
    k_reduce<<<64, 256, 0, stream>>>(partial, red);
    k_entries<<<512, 256, 0, stream>>>(red, blocksums);
    k_final<<<1, 256, 0, stream>>>(blocksums, out);
}

// Round 2
// 156.807 us; speedup vs baseline: 1.1739x; 1.1739x over previous
//
#include <hip/hip_runtime.h>
#include <cmath>

#define N_ 32
#define B_ 64
#define T_ 8192
#define CPB 16                      // chunks per b (t-chunks of 512)
#define PSTRIDE 2176                // 1024 pp + 1024 pn + 4*32 sums
#define PADH 264                    // LDS row pitch in halves (528 B, 16B-aligned)

typedef _Float16 half4 __attribute__((ext_vector_type(4)));
typedef _Float16 half8 __attribute__((ext_vector_type(8)));
typedef float floatx16 __attribute__((ext_vector_type(16)));

// ---------------- Stage 1: coalesced load -> LDS f16 tile -> MFMA Grams ----------------
// grid 1024 = 64 b * 16 chunks (512 t each); block 256 (4 waves).
// Pearson is invariant to the reference's per-n affine normalization, so raw data is used.
// Per 256-t step: 256 threads stage a [32 n x 256 t] f16 tile for both tensors
// (8 consecutive lanes read 8 consecutive float4s of one row -> full 128-B segments),
// then wave w consumes t-subrange [w*64, w*64+64) with 32x32x16 f16 MFMAs
// (A layout == B layout for this shape: one fragment serves both operands).
__global__ __launch_bounds__(256, 4) void k_stage1(const float* __restrict__ pos,
                                                   const float* __restrict__ neg,
                                                   float* __restrict__ partial) {
    __shared__ __align__(16) char smem[2 * 32 * PADH * 2];   // 33792 B
    _Float16(*tile)[32][PADH] = (_Float16(*)[32][PADH])smem; // tile[2][32][PADH]
    float* scratch = (float*)smem;                           // epilogue reuse (32768 B)

    const int bid = blockIdx.x;
    const int b = bid >> 4, c = bid & 15;
    const int tid = threadIdx.x;
    const int w = tid >> 6, lane = tid & 63;
    const int row = tid >> 3;    // 0..31 : Gram row this thread stages/sums
    const int oct = tid & 7;
    const int m = lane & 31, h = lane >> 5;

    const float* xrow = pos + ((long)row * B_ + b) * T_ + c * 512;
    const float* yrow = neg + ((long)row * B_ + b) * T_ + c * 512;

    floatx16 accpp = {};
    floatx16 accpn = {};
    float sx = 0.f, sx2 = 0.f, sy = 0.f, sy2 = 0.f;

#pragma unroll
    for (int s = 0; s < 2; ++s) {
        __syncthreads();   // tile free (no-op cost on s==0)
        const float4* px = (const float4*)(xrow + s * 256);
        const float4* py = (const float4*)(yrow + s * 256);
#pragma unroll
        for (int f = 0; f < 8; ++f) {
            float4 v = px[f * 8 + oct];
            sx += v.x + v.y + v.z + v.w;
            sx2 = fmaf(v.x, v.x, sx2); sx2 = fmaf(v.y, v.y, sx2);
            sx2 = fmaf(v.z, v.z, sx2); sx2 = fmaf(v.w, v.w, sx2);
            half4 hv = {(_Float16)v.x, (_Float16)v.y, (_Float16)v.z, (_Float16)v.w};
            *(half4*)&tile[0][row][f * 32 + oct * 4] = hv;

            float4 u = py[f * 8 + oct];
            sy += u.x + u.y + u.z + u.w;
            sy2 = fmaf(u.x, u.x, sy2); sy2 = fmaf(u.y, u.y, sy2);
            sy2 = fmaf(u.z, u.z, sy2); sy2 = fmaf(u.w, u.w, sy2);
            half4 hu = {(_Float16)u.x, (_Float16)u.y, (_Float16)u.z, (_Float16)u.w};
            *(half4*)&tile[1][row][f * 32 + oct * 4] = hu;
        }
        __syncthreads();   // tile ready
#pragma unroll
        for (int kk = 0; kk < 4; ++kk) {
            const int t0 = w * 64 + kk * 16 + h * 8;
            half8 xf = *(const half8*)&tile[0][m][t0];
            half8 yf = *(const half8*)&tile[1][m][t0];
            accpp = __builtin_amdgcn_mfma_f32_32x32x16_f16(xf, xf, accpp, 0, 0, 0);
            accpn = __builtin_amdgcn_mfma_f32_32x32x16_f16(xf, yf, accpn, 0, 0, 0);
        }
    }

    // per-row stats: octet lanes 0..7 share `row`; butterfly gives all lanes the totals
    sx += __shfl_xor(sx, 1); sx += __shfl_xor(sx, 2); sx += __shfl_xor(sx, 4);
    sx2 += __shfl_xor(sx2, 1); sx2 += __shfl_xor(sx2, 2); sx2 += __shfl_xor(sx2, 4);
    sy += __shfl_xor(sy, 1); sy += __shfl_xor(sy, 2); sy += __shfl_xor(sy, 4);
    sy2 += __shfl_xor(sy2, 1); sy2 += __shfl_xor(sy2, 2); sy2 += __shfl_xor(sy2, 4);

    float* out = partial + (long)bid * PSTRIDE;
    if (oct < 4) {
        float v = (oct == 0) ? sx : (oct == 1) ? sx2 : (oct == 2) ? sy : sy2;
        out[2048 + oct * 32 + row] = v;
    }

    // cross-wave Gram reduction via scratch (reuses tile memory)
    __syncthreads();   // all fragment reads done before overwrite
    // C/D layout (verified m74/m101): col = lane&31, row = (reg&3)+8*(reg>>2)+4*(lane>>5)
#pragma unroll
    for (int reg = 0; reg < 16; ++reg) {
        int rr = (reg & 3) + 8 * (reg >> 2) + 4 * h;
        scratch[w * 2048 + rr * 32 + m] = accpp[reg];
        scratch[w * 2048 + 1024 + rr * 32 + m] = accpn[reg];
    }
    __syncthreads();
    for (int o = tid; o < 2048; o += 256)
        out[o] = scratch[o] + scratch[2048 + o] + scratch[4096 + o] + scratch[6144 + o];
}

// ---------------- Stage 2: reduce 16 chunk partials -> per-b stats ----------------
// grid (17, 64), block 128: one thread per output element, coalesced strided sums.
__global__ void k_reduce(const float* __restrict__ partial, float* __restrict__ red) {
    const int b = blockIdx.y;
    const int o = blockIdx.x * 128 + threadIdx.x;   // 0..2175
    const float* in = partial + (long)b * CPB * PSTRIDE;
    float s = 0.f;
#pragma unroll
    for (int c = 0; c < CPB; ++c) s += in[c * PSTRIDE + o];
    red[(long)b * PSTRIDE + o] = s;
}

// ---------------- Stage 3: per-entry pearson over b, exp terms ----------------
// one wave per (matrix, n, m) entry; lane = b. grid 512 blocks * 4 waves = 2048 entries.
__global__ void k_entries(const float* __restrict__ red, double* __restrict__ blocksums) {
    const int tid = threadIdx.x;
    const int w = tid >> 6, lane = tid & 63;
    const int entry = blockIdx.x * 4 + w;
    const int mat = entry >> 10;       // 0 = pp, 1 = pn
    const int idx = entry & 1023;
    const int n = idx >> 5, m = idx & 31;

    const float* rb = red + (long)lane * PSTRIDE;
    float g = rb[mat * 1024 + idx];
    float sxn = rb[2048 + n];
    float sx2n = rb[2080 + n];
    float sym, sy2m;
    if (mat == 0) {
        sym = rb[2048 + m];
        sy2m = rb[2080 + m];
    } else {
        sym = rb[2112 + m];
        sy2m = rb[2144 + m];
    }

    double num = (double)T_ * (double)g - (double)sxn * (double)sym;
    double vx = (double)T_ * (double)sx2n - (double)sxn * (double)sxn;
    double vy = (double)T_ * (double)sy2m - (double)sym * (double)sym;
    double contrib = 1.0 - num / sqrt(vx * vy);

#pragma unroll
    for (int off = 32; off; off >>= 1) contrib += __shfl_down(contrib, off);

    __shared__ double s_pos[4], s_neg[4];
    if (lane == 0) {
        double d = contrib * (1.0 / B_);
        double term = exp(d / 0.08);
        double p = 0.0, q = 0.0;
        if (mat == 0) {
            if (n < m) p = term;     // strict upper triangle only
        } else {
            q = term;
        }
        s_pos[w] = p;
        s_neg[w] = q;
    }
    __syncthreads();
    if (tid == 0) {
        blocksums[blockIdx.x * 2 + 0] = s_pos[0] + s_pos[1] + s_pos[2] + s_pos[3];
        blocksums[blockIdx.x * 2 + 1] = s_neg[0] + s_neg[1] + s_neg[2] + s_neg[3];
    }
}

// ---------------- Stage 4: final scalar ----------------
__global__ void k_final(const double* __restrict__ blocksums, float* __restrict__ out) {
    __shared__ double sp[256], sn[256];
    const int tid = threadIdx.x;
    double p = 0.0, q = 0.0;
    for (int i = tid; i < 512; i += 256) {
        p += blocksums[2 * i + 0];
        q += blocksums[2 * i + 1];
    }
    sp[tid] = p;
    sn[tid] = q;
    __syncthreads();
    for (int s = 128; s; s >>= 1) {
        if (tid < s) {
            sp[tid] += sp[tid + s];
            sn[tid] += sn[tid + s];
        }
        __syncthreads();
    }
    if (tid == 0) out[0] = (float)log10(sp[0] / sn[0] + 1.0);
}

extern "C" void kernel_launch(void* const* d_in, const int* in_sizes, int n_in,
                              void* d_out, int out_size, void* d_ws, size_t ws_size,
                              hipStream_t stream) {
    const float* pos = (const float*)d_in[0];
    const float* neg = (const float*)d_in[1];
    float* out = (float*)d_out;

    char* ws = (char*)d_ws;
    float* partial = (float*)ws;                               // 1024*2176*4 = 8,912,896 B
    float* red = (float*)(ws + (size_t)1024 * PSTRIDE * 4);    //   64*2176*4 =   557,056 B
    double* blocksums = (double*)(ws + (size_t)1024 * PSTRIDE * 4 + (size_t)64 * PSTRIDE * 4);

    k_stage1<<<1024, 256, 0, stream>>>(pos, neg, partial);
    k_reduce<<<dim3(17, 64), 128, 0, stream>>>(partial, red);
    k_entries<<<512, 256, 0, stream>>>(red, blocksums);
    k_final<<<1, 256, 0, stream>>>(blocksums, out);
}

// Round 3
// 154.072 us; speedup vs baseline: 1.1947x; 1.0178x over previous
//
#include <hip/hip_runtime.h>
#include <cmath>

#define N_ 32
#define B_ 64
#define T_ 8192
#define CPB 16                      // t-chunks of 512 per b
#define PSTRIDE 2176                // 1024 pp + 1024 pn + 4*32 sums
#define PADH 264                    // LDS row pitch in halves (528 B = 33*16, 16B-aligned)

typedef _Float16 half4 __attribute__((ext_vector_type(4)));
typedef _Float16 half8 __attribute__((ext_vector_type(8)));
typedef float floatx4 __attribute__((ext_vector_type(4)));

// ---------------- Stage 1: coalesced load -> LDS f16 tile -> per-wave quadrant MFMA ----
// grid 1024 = 64 b * 16 chunks (512 t); block 512 (8 waves) -> 4 blocks/CU, 32 waves/CU.
// Pearson is invariant to the reference's per-n affine normalization -> use raw data.
// Each wave owns ONE 16x16 quadrant of ONE Gram (pp or pn): only 4 acc VGPRs, and the
// epilogue is a direct global store (no cross-wave reduction, no LDS scratch).
__global__ __launch_bounds__(512, 8) void k_stage1(const float* __restrict__ pos,
                                                   const float* __restrict__ neg,
                                                   float* __restrict__ partial) {
    __shared__ _Float16 tile[2][32][PADH];   // 33792 B

    const int bid = blockIdx.x;
    const int b = bid >> 4, c = bid & 15;
    const int tid = threadIdx.x;
    const int wave = tid >> 6, lane = tid & 63;
    const int row = tid >> 4;    // 0..31 : row this thread stages/sums (16 threads/row)
    const int idx = tid & 15;
    const int mat = wave >> 2;                 // 0 = pp, 1 = pn
    const int qi = (wave >> 1) & 1, qj = wave & 1;
    const int m16 = lane & 15, h2 = lane >> 4; // fragment coords

    const float* xrow = pos + ((long)row * B_ + b) * T_ + c * 512;
    const float* yrow = neg + ((long)row * B_ + b) * T_ + c * 512;

    floatx4 acc = {};
    float sx = 0.f, sx2 = 0.f, sy = 0.f, sy2 = 0.f;

#pragma unroll
    for (int s = 0; s < 2; ++s) {
        __syncthreads();   // tile free
        const float4* px = (const float4*)(xrow + s * 256);
        const float4* py = (const float4*)(yrow + s * 256);

        float4 vx[4], vy[4];
#pragma unroll
        for (int f = 0; f < 4; ++f) vx[f] = px[f * 16 + idx];
#pragma unroll
        for (int f = 0; f < 4; ++f) vy[f] = py[f * 16 + idx];
#pragma unroll
        for (int f = 0; f < 4; ++f) {
            float4 v = vx[f];
            sx += v.x + v.y + v.z + v.w;
            sx2 = fmaf(v.x, v.x, sx2); sx2 = fmaf(v.y, v.y, sx2);
            sx2 = fmaf(v.z, v.z, sx2); sx2 = fmaf(v.w, v.w, sx2);
            half4 hv = {(_Float16)v.x, (_Float16)v.y, (_Float16)v.z, (_Float16)v.w};
            *(half4*)&tile[0][row][(f * 16 + idx) * 4] = hv;
        }
#pragma unroll
        for (int f = 0; f < 4; ++f) {
            float4 u = vy[f];
            sy += u.x + u.y + u.z + u.w;
            sy2 = fmaf(u.x, u.x, sy2); sy2 = fmaf(u.y, u.y, sy2);
            sy2 = fmaf(u.z, u.z, sy2); sy2 = fmaf(u.w, u.w, sy2);
            half4 hu = {(_Float16)u.x, (_Float16)u.y, (_Float16)u.z, (_Float16)u.w};
            *(half4*)&tile[1][row][(f * 16 + idx) * 4] = hu;
        }
        __syncthreads();   // tile ready

        // A-operand layout (m120-verified): A[m = lane&15][k = (lane>>4)*8 + j].
        // Both fragments use the same layout -> mfma(x,y) = X . Y^T (the Gram).
        const _Float16* abase = &tile[0][qi * 16 + m16][h2 * 8];
        const _Float16* bbase = &tile[mat][qj * 16 + m16][h2 * 8];
#pragma unroll
        for (int k = 0; k < 8; ++k) {
            half8 af = *(const half8*)(abase + k * 32);
            half8 bf = *(const half8*)(bbase + k * 32);
            acc = __builtin_amdgcn_mfma_f32_16x16x32_f16(af, bf, acc, 0, 0, 0);
        }
    }

    // per-row stats: the 16 threads sharing `row` butterfly-reduce
    sx += __shfl_xor(sx, 1); sx += __shfl_xor(sx, 2);
    sx += __shfl_xor(sx, 4); sx += __shfl_xor(sx, 8);
    sx2 += __shfl_xor(sx2, 1); sx2 += __shfl_xor(sx2, 2);
    sx2 += __shfl_xor(sx2, 4); sx2 += __shfl_xor(sx2, 8);
    sy += __shfl_xor(sy, 1); sy += __shfl_xor(sy, 2);
    sy += __shfl_xor(sy, 4); sy += __shfl_xor(sy, 8);
    sy2 += __shfl_xor(sy2, 1); sy2 += __shfl_xor(sy2, 2);
    sy2 += __shfl_xor(sy2, 4); sy2 += __shfl_xor(sy2, 8);

    float* out = partial + (long)bid * PSTRIDE;
    if ((tid & 15) < 4) {
        int kind = tid & 3;
        float v = (kind == 0) ? sx : (kind == 1) ? sx2 : (kind == 2) ? sy : sy2;
        out[2048 + kind * 32 + row] = v;
    }

    // C/D layout 16x16 (m89-verified): col = lane&15, row = (lane>>4)*4 + reg
#pragma unroll
    for (int reg = 0; reg < 4; ++reg) {
        int rr = qi * 16 + h2 * 4 + reg;
        int cc = qj * 16 + m16;
        out[mat * 1024 + rr * 32 + cc] = acc[reg];
    }
}

// ---------------- Stage 2: reduce 16 chunk partials -> per-b stats ----------------
// grid (17, 64), block 128: one thread per output element, coalesced strided sums.
__global__ void k_reduce(const float* __restrict__ partial, float* __restrict__ red) {
    const int b = blockIdx.y;
    const int o = blockIdx.x * 128 + threadIdx.x;   // 0..2175
    const float* in = partial + (long)b * CPB * PSTRIDE;
    float s = 0.f;
#pragma unroll
    for (int c = 0; c < CPB; ++c) s += in[c * PSTRIDE + o];
    red[(long)b * PSTRIDE + o] = s;
}

// ---------------- Stage 3: per-entry pearson over b, exp terms ----------------
// one wave per (matrix, n, m) entry; lane = b. grid 512 blocks * 4 waves = 2048 entries.
__global__ void k_entries(const float* __restrict__ red, double* __restrict__ blocksums) {
    const int tid = threadIdx.x;
    const int w = tid >> 6, lane = tid & 63;
    const int entry = blockIdx.x * 4 + w;
    const int mat = entry >> 10;       // 0 = pp, 1 = pn
    const int idx = entry & 1023;
    const int n = idx >> 5, m = idx & 31;

    const float* rb = red + (long)lane * PSTRIDE;
    float g = rb[mat * 1024 + idx];
    float sxn = rb[2048 + n];
    float sx2n = rb[2080 + n];
    float sym, sy2m;
    if (mat == 0) {
        sym = rb[2048 + m];
        sy2m = rb[2080 + m];
    } else {
        sym = rb[2112 + m];
        sy2m = rb[2144 + m];
    }

    double num = (double)T_ * (double)g - (double)sxn * (double)sym;
    double vx = (double)T_ * (double)sx2n - (double)sxn * (double)sxn;
    double vy = (double)T_ * (double)sy2m - (double)sym * (double)sym;
    double contrib = 1.0 - num / sqrt(vx * vy);

#pragma unroll
    for (int off = 32; off; off >>= 1) contrib += __shfl_down(contrib, off);

    __shared__ double s_pos[4], s_neg[4];
    if (lane == 0) {
        double d = contrib * (1.0 / B_);
        double term = exp(d / 0.08);
        double p = 0.0, q = 0.0;
        if (mat == 0) {
            if (n < m) p = term;     // strict upper triangle only
        } else {
            q = term;
        }
        s_pos[w] = p;
        s_neg[w] = q;
    }
    __syncthreads();
    if (tid == 0) {
        blocksums[blockIdx.x * 2 + 0] = s_pos[0] + s_pos[1] + s_pos[2] + s_pos[3];
        blocksums[blockIdx.x * 2 + 1] = s_neg[0] + s_neg[1] + s_neg[2] + s_neg[3];
    }
}

// ---------------- Stage 4: final scalar ----------------
__global__ void k_final(const double* __restrict__ blocksums, float* __restrict__ out) {
    __shared__ double sp[256], sn[256];
    const int tid = threadIdx.x;
    double p = 0.0, q = 0.0;
    for (int i = tid; i < 512; i += 256) {
        p += blocksums[2 * i + 0];
        q += blocksums[2 * i + 1];
    }
    sp[tid] = p;
    sn[tid] = q;
    __syncthreads();
    for (int s = 128; s; s >>= 1) {
        if (tid < s) {
            sp[tid] += sp[tid + s];
            sn[tid] += sn[tid + s];
        }
        __syncthreads();
    }
    if (tid == 0) out[0] = (float)log10(sp[0] / sn[0] + 1.0);
}

extern "C" void kernel_launch(void* const* d_in, const int* in_sizes, int n_in,
                              void* d_out, int out_size, void* d_ws, size_t ws_size,
                              hipStream_t stream) {
    const float* pos = (const float*)d_in[0];
    const float* neg = (const float*)d_in[1];
    float* out = (float*)d_out;

    char* ws = (char*)d_ws;
    float* partial = (float*)ws;                               // 1024*2176*4 = 8,912,896 B
    float* red = (float*)(ws + (size_t)1024 * PSTRIDE * 4);    //   64*2176*4 =   557,056 B
    double* blocksums = (double*)(ws + (size_t)1024 * PSTRIDE * 4 + (size_t)64 * PSTRIDE * 4);

    k_stage1<<<1024, 512, 0, stream>>>(pos, neg, partial);
    k_reduce<<<dim3(17, 64), 128, 0, stream>>>(partial, red);
    k_entries<<<512, 256, 0, stream>>>(red, blocksums);
    k_final<<<1, 256, 0, stream>>>(blocksums, out);
}